// Round 1
// baseline (522.789 us; speedup 1.0000x reference)
//
#include <hip/hip_runtime.h>

typedef unsigned short u16;
typedef short bf16x8 __attribute__((ext_vector_type(8)));
typedef float f32x4 __attribute__((ext_vector_type(4)));

#define MFMA16 __builtin_amdgcn_mfma_f32_16x16x32_bf16

// Constants for this problem
// B=4, S=2048, H=12, DH=64, D=768, M = B*S = 8192

__device__ __forceinline__ u16 f2b(float f) {
    unsigned int u = __builtin_bit_cast(unsigned int, f);
    u = (u + 0x7fffu + ((u >> 16) & 1u)) >> 16;
    return (u16)u;
}

// ---------------- convert x fp32 -> bf16 (vectorized, 4 elems/thread) ----------------
__global__ __launch_bounds__(256) void convert_f32_bf16(const float* __restrict__ in,
                                                        u16* __restrict__ out, int n4) {
    int i = blockIdx.x * 256 + threadIdx.x;
    if (i >= n4) return;
    float4 v = ((const float4*)in)[i];
    ushort4 o;
    o.x = f2b(v.x); o.y = f2b(v.y); o.z = f2b(v.z); o.w = f2b(v.w);
    ((ushort4*)out)[i] = o;
}

// ---------------- W_Q/K/V [h,d,e] -> Wt[n=h*64+e][d] bf16 ----------------
__global__ __launch_bounds__(256) void prep_w_qkv(const float* __restrict__ W,
                                                  u16* __restrict__ Wt) {
    int tid = blockIdx.x * 256 + threadIdx.x;  // 768*768
    int d = tid % 768;
    int n = tid / 768;
    Wt[tid] = f2b(W[(n >> 6) * 49152 + d * 64 + (n & 63)]);
}

// ---------------- W_O [h,e,d] = [k][d] -> Wt[d][k] bf16 (plain transpose) ----------------
__global__ __launch_bounds__(256) void prep_w_o(const float* __restrict__ W,
                                                u16* __restrict__ Wt) {
    int tid = blockIdx.x * 256 + threadIdx.x;  // 768*768
    int k = tid % 768;
    int d = tid / 768;
    Wt[tid] = f2b(W[k * 768 + d]);  // Wt[d*768 + k]
}

// ---------------- GEMM: C[M=8192][N=768] = A[M][768] * Bt[N][768]^T ----------------
// mode 0: out bf16 scatter to [b,h,s,e]; val = (acc + bias[n]) * scale
// mode 1: out fp32 [m][n];               val = acc + bias[n]
__global__ __launch_bounds__(256) void gemm_kernel(
    const u16* __restrict__ A, const u16* __restrict__ Bt,
    const float* __restrict__ bias, float scale, int mode,
    u16* __restrict__ outb, float* __restrict__ outf) {
    __shared__ u16 As[64][40];  // pad 32->40 to break bank aliasing
    __shared__ u16 Bs[64][40];
    const int m0 = blockIdx.x * 64, n0 = blockIdx.y * 64;
    const int t = threadIdx.x;
    const int wave = t >> 6, lane = t & 63, l15 = lane & 15, quad = lane >> 4;
    const int srow = t >> 2, scol = (t & 3) * 8;

    f32x4 acc[4] = {};
    const u16* Aptr = A + (size_t)(m0 + srow) * 768 + scol;
    const u16* Bptr = Bt + (size_t)(n0 + srow) * 768 + scol;

    for (int kt = 0; kt < 24; ++kt) {
        __syncthreads();
        *(int4*)&As[srow][scol] = *(const int4*)(Aptr + kt * 32);
        *(int4*)&Bs[srow][scol] = *(const int4*)(Bptr + kt * 32);
        __syncthreads();
        bf16x8 a = *(bf16x8*)&As[wave * 16 + l15][quad * 8];
#pragma unroll
        for (int nt = 0; nt < 4; ++nt) {
            bf16x8 b = *(bf16x8*)&Bs[nt * 16 + l15][quad * 8];
            acc[nt] = MFMA16(a, b, acc[nt], 0, 0, 0);
        }
    }
#pragma unroll
    for (int nt = 0; nt < 4; ++nt) {
        int n = n0 + nt * 16 + l15;
        float bi = bias[n];
#pragma unroll
        for (int r = 0; r < 4; ++r) {
            int m = m0 + wave * 16 + quad * 4 + r;
            float val = (acc[nt][r] + bi) * scale;
            if (mode == 0) {
                int b = m >> 11, s = m & 2047, h = n >> 6, e = n & 63;
                outb[((size_t)(b * 12 + h) * 2048 + s) * 64 + e] = f2b(val);
            } else {
                outf[(size_t)m * 768 + n] = val;
            }
        }
    }
}

// ---------------- Flash attention: block = (b, h, 64-row q tile) ----------------
__global__ __launch_bounds__(256) void attn_kernel(
    const u16* __restrict__ q, const u16* __restrict__ k,
    const u16* __restrict__ v, u16* __restrict__ z) {
    __shared__ u16 Qs[64][72];      // [qrow][e], pad 64->72
    __shared__ u16 Vt[64][40];      // [e][kk], pad 32->40
    __shared__ u16 Ps[4][16][40];   // per-wave P round-trip
    const int qt = blockIdx.x, h = blockIdx.y, b = blockIdx.z;
    const int t = threadIdx.x;
    const int wave = t >> 6, lane = t & 63, l15 = lane & 15, quad = lane >> 4;
    const int qbase = qt * 64;
    const size_t head_off = (size_t)(b * 12 + h) * 2048 * 64;

    {   // stage Q tile (coalesced 16B loads)
        int row = t >> 2, e0 = (t & 3) * 16;
        const u16* src = q + head_off + (size_t)(qbase + row) * 64 + e0;
        *(int4*)&Qs[row][e0] = *(const int4*)src;
        *(int4*)&Qs[row][e0 + 8] = *(const int4*)(src + 8);
    }

    f32x4 accs[4] = {};
    float m_i[4], l_i[4];
#pragma unroll
    for (int r = 0; r < 4; ++r) { m_i[r] = -1e30f; l_i[r] = 0.f; }

    const int ktmax = qt * 2 + 2;
    for (int kt = 0; kt < ktmax; ++kt) {
        const int kbase = kt * 32;
        __syncthreads();  // protects Vt/Ps from prev iter; Qs visible at kt==0
        {   // stage V tile transposed: Vt[e][kk]
            int kk = t >> 3, e0 = (t & 7) * 8;
            const u16* src = v + head_off + (size_t)(kbase + kk) * 64 + e0;
            union { int4 v4; u16 s[8]; } raw;
            raw.v4 = *(const int4*)src;
#pragma unroll
            for (int j = 0; j < 8; ++j) Vt[e0 + j][kk] = raw.s[j];
        }
        // S = Q K^T  (K B-frags straight from global: contiguous along e)
        bf16x8 aq0 = *(bf16x8*)&Qs[wave * 16 + l15][quad * 8];
        bf16x8 aq1 = *(bf16x8*)&Qs[wave * 16 + l15][32 + quad * 8];
        f32x4 sa[2] = {};
#pragma unroll
        for (int nt = 0; nt < 2; ++nt) {
            const u16* krow = k + head_off + (size_t)(kbase + nt * 16 + l15) * 64;
            bf16x8 bk0 = *(const bf16x8*)(krow + quad * 8);
            bf16x8 bk1 = *(const bf16x8*)(krow + 32 + quad * 8);
            sa[nt] = MFMA16(aq0, bk0, sa[nt], 0, 0, 0);
            sa[nt] = MFMA16(aq1, bk1, sa[nt], 0, 0, 0);
        }
        // online softmax (per q-row stats live in the 16-lane quad)
#pragma unroll
        for (int r = 0; r < 4; ++r) {
            int qrow = qbase + wave * 16 + quad * 4 + r;
            float s0 = sa[0][r]; if (kbase + l15 > qrow) s0 = -1e30f;
            float s1 = sa[1][r]; if (kbase + 16 + l15 > qrow) s1 = -1e30f;
            float mx = fmaxf(s0, s1);
#pragma unroll
            for (int off = 8; off >= 1; off >>= 1) mx = fmaxf(mx, __shfl_xor(mx, off));
            float newm = fmaxf(m_i[r], mx);
            float alpha = __expf(m_i[r] - newm);
            float p0 = __expf(s0 - newm), p1 = __expf(s1 - newm);
            float rs = p0 + p1;
#pragma unroll
            for (int off = 8; off >= 1; off >>= 1) rs += __shfl_xor(rs, off);
            l_i[r] = l_i[r] * alpha + rs;
            m_i[r] = newm;
#pragma unroll
            for (int nt = 0; nt < 4; ++nt) accs[nt][r] *= alpha;
            Ps[wave][quad * 4 + r][l15] = f2b(p0);
            Ps[wave][quad * 4 + r][16 + l15] = f2b(p1);
        }
        __syncthreads();  // Vt staged by all; Ps write->read ordering
        // O += P V
        bf16x8 ap = *(bf16x8*)&Ps[wave][l15][quad * 8];
#pragma unroll
        for (int nt = 0; nt < 4; ++nt) {
            bf16x8 bv = *(bf16x8*)&Vt[nt * 16 + l15][quad * 8];
            accs[nt] = MFMA16(ap, bv, accs[nt], 0, 0, 0);
        }
    }
    // epilogue: z[b, s, h, e] bf16
#pragma unroll
    for (int r = 0; r < 4; ++r) {
        float inv = 1.0f / l_i[r];
        int qrow = qbase + wave * 16 + quad * 4 + r;
        u16* dst = z + ((size_t)(b * 2048 + qrow) * 12 + h) * 64;
#pragma unroll
        for (int nt = 0; nt < 4; ++nt) dst[nt * 16 + l15] = f2b(accs[nt][r] * inv);
    }
}

extern "C" void kernel_launch(void* const* d_in, const int* in_sizes, int n_in,
                              void* d_out, int out_size, void* d_ws, size_t ws_size,
                              hipStream_t stream) {
    const float* x  = (const float*)d_in[0];
    const float* WQ = (const float*)d_in[1];
    const float* WK = (const float*)d_in[2];
    const float* WV = (const float*)d_in[3];
    const float* WO = (const float*)d_in[4];
    const float* bQ = (const float*)d_in[5];
    const float* bK = (const float*)d_in[6];
    const float* bV = (const float*)d_in[7];
    const float* bO = (const float*)d_in[8];
    float* out = (float*)d_out;

    char* ws = (char*)d_ws;
    u16* xb  = (u16*)(ws);                    // 8192*768 bf16 = 12582912 B
    u16* wtq = (u16*)(ws + 12582912);         // 768*768 bf16 = 1179648 B
    u16* wtk = (u16*)(ws + 13762560);
    u16* wtv = (u16*)(ws + 14942208);
    u16* wto = (u16*)(ws + 16121856);
    u16* qb  = (u16*)(ws + 17301504);         // [b,h,s,e] bf16 = 12582912 B
    u16* kb  = (u16*)(ws + 29884416);
    u16* vb  = (u16*)(ws + 42467328);
    u16* zb  = (u16*)(ws + 55050240);         // [b,s,h,e] bf16 = 12582912 B

    // 1. x -> bf16
    convert_f32_bf16<<<6144, 256, 0, stream>>>(x, xb, 1572864);
    // 2. weight prep
    prep_w_qkv<<<2304, 256, 0, stream>>>(WQ, wtq);
    prep_w_qkv<<<2304, 256, 0, stream>>>(WK, wtk);
    prep_w_qkv<<<2304, 256, 0, stream>>>(WV, wtv);
    prep_w_o  <<<2304, 256, 0, stream>>>(WO, wto);
    // 3. QKV projections (Q gets the 1/sqrt(64) fused)
    dim3 ggrid(128, 12);
    gemm_kernel<<<ggrid, 256, 0, stream>>>(xb, wtq, bQ, 0.125f, 0, qb, nullptr);
    gemm_kernel<<<ggrid, 256, 0, stream>>>(xb, wtk, bK, 1.0f,   0, kb, nullptr);
    gemm_kernel<<<ggrid, 256, 0, stream>>>(xb, wtv, bV, 1.0f,   0, vb, nullptr);
    // 4. causal flash attention
    dim3 agrid(32, 12, 4);
    attn_kernel<<<agrid, 256, 0, stream>>>(qb, kb, vb, zb);
    // 5. output projection (fp32 out + b_O)
    gemm_kernel<<<ggrid, 256, 0, stream>>>(zb, wto, bO, 1.0f, 1, nullptr, out);
}